// Round 15
// baseline (205.032 us; speedup 1.0000x reference)
//
#include <hip/hip_runtime.h>
#include <stdint.h>

// MH_gate — R11: QKV GEMM retiled 128x128 -> 128x64 for occupancy (5th submit;
// R11-R14 benches hit infra timeouts, kernel never measured).
// R9 data: QKV 35.2us, MfmaUtil 15%, VALUBusy 9%, HBM 8%, Occupancy 12%,
// VGPR 208 (2 waves/SIMD -> 2 blocks/CU). Latency-bound: every K-step pays an
// un-overlapped L2/L3 round-trip. R10's swizzle was null — correctly so:
// SQ_LDS_BANK_CONFLICT 2.5e7 = 7% of cycles, and wave64 b128 reads were
// already at the 8/bank bandwidth floor. (Lesson: quantify counters vs cycle
// budget.) Fix: per-wave 32x64 subtiles (acc[2][4]=32 VGPR), grid 64x24=1536,
// __launch_bounds__(256,4) -> ~4 blocks/CU of cross-block latency overlap.
// Predicted: QKV 35 -> 18-22us, dur 202 -> 185-190. Null => L3-BW-bound,
// next lever is arithmetic intensity, not parallelism.
// CONTRACT: float inputs fp32 storage (bf16-rounded values), out fp32,
// use_adj int32. Mask: adj in {0,1} -> s*adj. exp via exp2, log2e folded in q.
// History: R3 occ null (h/O), R4 dbuf null, R6 fusion null (envelope ~105us
// masks), R9 instrumentation: kernel sum ~100us, QKV biggest single target.

typedef __bf16 bf16_t;
typedef __bf16 bf16x8 __attribute__((ext_vector_type(8)));
typedef float  f32x4  __attribute__((ext_vector_type(4)));

#define B_   16
#define N_   512
#define D_   512
#define H_   8
#define DK_  64
#define BN_  8192
#define LOG2E 1.4426950408889634f

// ---- async global->LDS, 16B per lane --------------------------------------------
__device__ __forceinline__ void gl2lds16(const void* g, void* l) {
  __builtin_amdgcn_global_load_lds(
      (const __attribute__((address_space(1))) void*)g,
      (__attribute__((address_space(3))) void*)l, 16, 0, 0);
}

// ---- merged prep: x cast (blocks 0..2047), W^T (2048..3327) ----------------------
struct WPrep { const float* src[5]; bf16_t* dst[5]; };
__global__ __launch_bounds__(256) void k_prep(const float* __restrict__ x,
                                              bf16_t* __restrict__ xb,
                                              WPrep p) {
  __shared__ float tile[32][33];
  const int blk = blockIdx.x;
  const int t = threadIdx.x;
  if (blk < 2048) {               // x fp32 -> bf16 (lossless: bf16-rounded values)
    const long i = ((long)blk * 256 + t) * 8;
    float4 a = *(const float4*)&x[i];
    float4 b = *(const float4*)&x[i + 4];
    bf16x8 o;
    o[0] = (bf16_t)a.x; o[1] = (bf16_t)a.y; o[2] = (bf16_t)a.z; o[3] = (bf16_t)a.w;
    o[4] = (bf16_t)b.x; o[5] = (bf16_t)b.y; o[6] = (bf16_t)b.z; o[7] = (bf16_t)b.w;
    *(bf16x8*)&xb[i] = o;
  } else {                        // Wt[n][k] = bf16(W[k][n]), 5 weights
    const int r = blk - 2048;
    const int z = r >> 8, rem = r & 255;
    const float* W = p.src[z];
    bf16_t* Wt = p.dst[z];
    const int kb = (rem & 15) * 32, nb = (rem >> 4) * 32;
    const int tx = t & 31, ty = t >> 5;
#pragma unroll
    for (int i = ty; i < 32; i += 8)
      tile[i][tx] = W[(long)(kb + i) * D_ + nb + tx];
    __syncthreads();
#pragma unroll
    for (int i = ty; i < 32; i += 8)
      Wt[(long)(nb + i) * D_ + kb + tx] = (bf16_t)tile[tx][i];
  }
}

// Swizzle helpers (both-sides involution, proven neutral R10, kept for min-diff):
//   stage thread t: row = t>>2, phys 16B-slot = t&3 -> fetch global slot
//   (t&3) ^ ((t>>3)&3); read lane: slot = quad ^ ((l16>>1)&3).

// ---- row-owning 32x512 GEMM with fused row-wise epilogue -------------------------
// MODE 0: LN  — out bf16 = (v-mu)*rstd*g + b,  v = A@Bt^T + bias
// MODE 1: gate — h2 = relu(v); z = x.gw0 + h2.gw1 + gb; out fp32 = c*x+(1-c)*h2
template <int MODE>
__global__ __launch_bounds__(512) void k_gemm_row(const bf16_t* __restrict__ A,
                                                  const bf16_t* __restrict__ Bt,
                                                  const float* __restrict__ bias,
                                                  const float* __restrict__ p0,
                                                  const float* __restrict__ p1,
                                                  const float* __restrict__ p2,
                                                  void* __restrict__ outp) {
  __shared__ bf16_t As[2][32 * 32];
  __shared__ bf16_t Bs[2][512 * 32];
  __shared__ float red[8][32][2];
  __shared__ float rowc[32][2];
  const int t = threadIdx.x;
  const int w = t >> 6, lane = t & 63;
  const int quad = lane >> 4, l16 = lane & 15;
  const int m0 = blockIdx.x * 32;
  const int wn = w * 64;

  const int ea = t * 8;
  const int scol = (((t & 3) ^ ((t >> 3) & 3)) * 8);
  const bf16_t* agp = A + (long)(m0 + (t >> 2)) * 512 + scol;
  const bf16_t* bgp[4];
  int eb[4];
#pragma unroll
  for (int j = 0; j < 4; ++j) {
    eb[j] = j * 4096 + t * 8;
    bgp[j] = Bt + (long)(j * 128 + (t >> 2)) * 512 + scol;
  }

  const int csw = (quad ^ ((l16 >> 1) & 3)) * 8;

  f32x4 acc[2][4] = {};

  if (t < 128) gl2lds16(agp, &As[0][ea]);
#pragma unroll
  for (int j = 0; j < 4; ++j) gl2lds16(bgp[j], &Bs[0][eb[j]]);
  __syncthreads();

  int cur = 0;
  for (int k0 = 0; k0 < 512; k0 += 32) {
    const int nxt = cur ^ 1;
    if (k0 + 32 < 512) {
      if (t < 128) gl2lds16(agp + k0 + 32, &As[nxt][ea]);
#pragma unroll
      for (int j = 0; j < 4; ++j) gl2lds16(bgp[j] + k0 + 32, &Bs[nxt][eb[j]]);
    }
    bf16x8 af[2], bfr[4];
#pragma unroll
    for (int mi = 0; mi < 2; ++mi)
      af[mi] = *(const bf16x8*)&As[cur][(mi * 16 + l16) * 32 + csw];
#pragma unroll
    for (int ni = 0; ni < 4; ++ni)
      bfr[ni] = *(const bf16x8*)&Bs[cur][(wn + ni * 16 + l16) * 32 + csw];
#pragma unroll
    for (int mi = 0; mi < 2; ++mi)
#pragma unroll
      for (int ni = 0; ni < 4; ++ni)
        acc[mi][ni] = __builtin_amdgcn_mfma_f32_16x16x32_bf16(af[mi], bfr[ni],
                                                              acc[mi][ni], 0, 0, 0);
    __syncthreads();
    cur = nxt;
  }

  float bv[4];
#pragma unroll
  for (int ni = 0; ni < 4; ++ni) bv[ni] = bias[wn + ni * 16 + l16];

  if (MODE == 0) {
    // ---- LayerNorm epilogue ----
#pragma unroll
    for (int mi = 0; mi < 2; ++mi)
#pragma unroll
      for (int r = 0; r < 4; ++r) {
        float s1 = 0.f, s2 = 0.f;
#pragma unroll
        for (int ni = 0; ni < 4; ++ni) {
          const float v = acc[mi][ni][r] + bv[ni];
          s1 += v; s2 += v * v;
        }
#pragma unroll
        for (int o = 1; o < 16; o <<= 1) {
          s1 += __shfl_xor(s1, o, 64);
          s2 += __shfl_xor(s2, o, 64);
        }
        if (l16 == 0) {
          const int row = mi * 16 + quad * 4 + r;
          red[w][row][0] = s1; red[w][row][1] = s2;
        }
      }
    __syncthreads();
    if (t < 32) {
      float S1 = 0.f, S2 = 0.f;
#pragma unroll
      for (int wv = 0; wv < 8; ++wv) { S1 += red[wv][t][0]; S2 += red[wv][t][1]; }
      const float mu = S1 * (1.0f / 512.0f);
      const float var = S2 * (1.0f / 512.0f) - mu * mu;
      rowc[t][0] = mu;
      rowc[t][1] = rsqrtf(var + 1e-5f);
    }
    __syncthreads();
    float gv[4], b2[4];
#pragma unroll
    for (int ni = 0; ni < 4; ++ni) {
      gv[ni] = p0[wn + ni * 16 + l16];
      b2[ni] = p1[wn + ni * 16 + l16];
    }
#pragma unroll
    for (int mi = 0; mi < 2; ++mi)
#pragma unroll
      for (int r = 0; r < 4; ++r) {
        const int row = mi * 16 + quad * 4 + r;
        const float mu = rowc[row][0], rs = rowc[row][1];
#pragma unroll
        for (int ni = 0; ni < 4; ++ni) {
          const float v = acc[mi][ni][r] + bv[ni];
          ((bf16_t*)outp)[(long)(m0 + row) * 512 + wn + ni * 16 + l16] =
              (bf16_t)((v - mu) * rs * gv[ni] + b2[ni]);
        }
      }
  } else {
    // ---- ReLU + gate epilogue ----
    float g0[4], g1[4];
#pragma unroll
    for (int ni = 0; ni < 4; ++ni) {
      g0[ni] = p1[wn + ni * 16 + l16];
      g1[ni] = p1[512 + wn + ni * 16 + l16];
    }
    float xr[2][4][4];
#pragma unroll
    for (int mi = 0; mi < 2; ++mi)
#pragma unroll
      for (int r = 0; r < 4; ++r) {
        const int row = mi * 16 + quad * 4 + r;
#pragma unroll
        for (int ni = 0; ni < 4; ++ni)
          xr[mi][ni][r] = p0[(long)(m0 + row) * 512 + wn + ni * 16 + l16];
      }
#pragma unroll
    for (int mi = 0; mi < 2; ++mi)
#pragma unroll
      for (int r = 0; r < 4; ++r) {
        float px = 0.f, ph = 0.f;
#pragma unroll
        for (int ni = 0; ni < 4; ++ni) {
          const float h2 = fmaxf(acc[mi][ni][r] + bv[ni], 0.0f);
          px += xr[mi][ni][r] * g0[ni];
          ph += h2 * g1[ni];
        }
#pragma unroll
        for (int o = 1; o < 16; o <<= 1) {
          px += __shfl_xor(px, o, 64);
          ph += __shfl_xor(ph, o, 64);
        }
        if (l16 == 0) {
          const int row = mi * 16 + quad * 4 + r;
          red[w][row][0] = px; red[w][row][1] = ph;
        }
      }
    __syncthreads();
    if (t < 32) {
      float z = p2[0];
#pragma unroll
      for (int wv = 0; wv < 8; ++wv) z += red[wv][t][0] + red[wv][t][1];
      rowc[t][0] = 1.0f / (1.0f + __expf(-z));
    }
    __syncthreads();
#pragma unroll
    for (int mi = 0; mi < 2; ++mi)
#pragma unroll
      for (int r = 0; r < 4; ++r) {
        const int row = mi * 16 + quad * 4 + r;
        const float c = rowc[row][0];
#pragma unroll
        for (int ni = 0; ni < 4; ++ni) {
          const float h2 = fmaxf(acc[mi][ni][r] + bv[ni], 0.0f);
          ((float*)outp)[(long)(m0 + row) * 512 + wn + ni * 16 + l16] =
              c * xr[mi][ni][r] + (1.0f - c) * h2;
        }
      }
  }
}

// ---- 128x64 GEMM, QKV mode (R11: occupancy-tiled) --------------------------------
// Per-wave 32x64 subtile: acc[2][4]=32 VGPR. Grid 64x24 = 1536 blocks.
// seg<2 (q,k) -> bf16 qk buffer (ld 1024); seg==2 (v) -> vT[((b*8+h)*64+dk)*512+tok].
__global__ __launch_bounds__(256, 4) void k_gemm_qkv(const bf16_t* __restrict__ A,
                                                     const bf16_t* __restrict__ Bt,
                                                     const float* __restrict__ b0,
                                                     const float* __restrict__ b1,
                                                     const float* __restrict__ b2,
                                                     float s0,
                                                     bf16_t* __restrict__ outp,
                                                     bf16_t* __restrict__ vtp) {
  __shared__ bf16_t As[2][128 * 32];
  __shared__ bf16_t Bs[2][64 * 32];
  const int t = threadIdx.x;
  const int m0 = blockIdx.x * 128;
  const int n0 = blockIdx.y * 64;
  const int w = t >> 6, lane = t & 63;
  const int quad = lane >> 4, l16 = lane & 15;
  const int wm = w * 32;                               // 4 waves x 32 m-rows

  const int e0 = t * 8;
  const int r0 = t >> 2;
  const int scol = (((t & 3) ^ ((t >> 3) & 3)) * 8);   // pre-swizzled source col
  const bf16_t* agp0 = A + (long)(m0 + r0) * 512 + scol;
  const bf16_t* agp1 = agp0 + (long)64 * 512;          // rows+64: same swizzle bits
  const bf16_t* bgp0 = Bt + (long)(n0 + r0) * 512 + scol;  // 64 B-rows: 1 load

  const int csw = (quad ^ ((l16 >> 1) & 3)) * 8;       // swizzled read col

  f32x4 acc[2][4] = {};

  gl2lds16(agp0, &As[0][e0]);
  gl2lds16(agp1, &As[0][e0 + 2048]);
  gl2lds16(bgp0, &Bs[0][e0]);
  __syncthreads();

  int cur = 0;
  for (int k0 = 0; k0 < 512; k0 += 32) {
    const int nxt = cur ^ 1;
    if (k0 + 32 < 512) {
      gl2lds16(agp0 + k0 + 32, &As[nxt][e0]);
      gl2lds16(agp1 + k0 + 32, &As[nxt][e0 + 2048]);
      gl2lds16(bgp0 + k0 + 32, &Bs[nxt][e0]);
    }
    bf16x8 af[2], bfr[4];
#pragma unroll
    for (int i = 0; i < 2; ++i)
      af[i]  = *(const bf16x8*)&As[cur][(wm + i * 16 + l16) * 32 + csw];
#pragma unroll
    for (int i = 0; i < 4; ++i)
      bfr[i] = *(const bf16x8*)&Bs[cur][(i * 16 + l16) * 32 + csw];
#pragma unroll
    for (int mi = 0; mi < 2; ++mi)
#pragma unroll
      for (int ni = 0; ni < 4; ++ni)
        acc[mi][ni] = __builtin_amdgcn_mfma_f32_16x16x32_bf16(af[mi], bfr[ni],
                                                              acc[mi][ni], 0, 0, 0);
    __syncthreads();
    cur = nxt;
  }

  const int seg = n0 >> 9;
  const float* bias = (seg == 0) ? b0 : (seg == 1) ? b1 : b2;
  const float scale = (seg == 0) ? s0 : 1.0f;
#pragma unroll
  for (int ni = 0; ni < 4; ++ni) {
    const int n = n0 + ni * 16 + l16;
    const float bvv = bias[n & 511];
#pragma unroll
    for (int mi = 0; mi < 2; ++mi)
#pragma unroll
      for (int r = 0; r < 4; ++r) {
        const long m = m0 + wm + mi * 16 + quad * 4 + r;
        const float v = (acc[mi][ni][r] + bvv) * scale;
        if (seg < 2) {
          outp[m * 1024 + n] = (bf16_t)v;
        } else {
          const int tok = (int)m & 511, bb = (int)(m >> 9);
          const int hh = (n >> 6) & 7, dk = n & 63;
          vtp[(((long)bb * 8 + hh) * 64 + dk) * 512 + tok] = (bf16_t)v;
        }
      }
  }
}

// ---- MFMA flash attention: 64 q-rows/block, 1024 blocks, XCD-swizzled ------------
// q pre-scaled by SCALE*log2e -> exp(s) = v_exp_f32(s). Mask: s *= adj ({0,1}).
__global__ __launch_bounds__(256) void k_attn(const bf16_t* __restrict__ qk,
                                              const bf16_t* __restrict__ vT,
                                              const float* __restrict__ adj,
                                              const int* __restrict__ use_adj_p,
                                              bf16_t* __restrict__ ctx) {
  __shared__ bf16_t Ks[64][72];
  __shared__ bf16_t Vs[64][72];
  __shared__ bf16_t Ps[4][16][72];
  const int t = threadIdx.x;
  const int w = t >> 6, lane = t & 63;
  const int quad = lane >> 4, l16 = lane & 15;
  const int bh = blockIdx.x & 127;   // XCD swizzle: same head -> same XCD
  const int qt = blockIdx.x >> 7;
  const int b = bh >> 3, h = bh & 7;
  const int q0 = qt * 64;
  const int use_adj = use_adj_p[0];

  const long qoff = (long)(b * N_ + q0 + w * 16 + l16) * 1024 + h * DK_ + quad * 8;
  const bf16x8 aq0 = *(const bf16x8*)&qk[qoff];
  const bf16x8 aq1 = *(const bf16x8*)&qk[qoff + 32];

  const int sr = t >> 2, sc = (t & 3) * 16;
  const bf16_t* kbase  = qk + (long)b * N_ * 1024 + 512 + h * DK_;
  const bf16_t* vtbase = vT + (long)bh * DK_ * N_;
  const float*  abase  = adj + ((long)b * N_ + q0 + w * 16 + quad * 4) * N_;

  f32x4 accO[4] = {};
  float l_part[4] = {0.f, 0.f, 0.f, 0.f};

  for (int kt = 0; kt < 8; ++kt) {
    __syncthreads();
    {
      const bf16_t* ksrc = kbase + (long)(kt * 64 + sr) * 1024 + sc;
      *(uint4*)&Ks[sr][sc]     = *(const uint4*)ksrc;
      *(uint4*)&Ks[sr][sc + 8] = *(const uint4*)(ksrc + 8);
      const bf16_t* vsrc = vtbase + (long)sr * N_ + kt * 64 + sc;
      *(uint4*)&Vs[sr][sc]     = *(const uint4*)vsrc;
      *(uint4*)&Vs[sr][sc + 8] = *(const uint4*)(vsrc + 8);
    }
    __syncthreads();

    // S = Q K^T (16 x 64)
    f32x4 s[4];
#pragma unroll
    for (int nt = 0; nt < 4; ++nt) {
      bf16x8 bk0 = *(const bf16x8*)&Ks[nt * 16 + l16][quad * 8];
      bf16x8 bk1 = *(const bf16x8*)&Ks[nt * 16 + l16][quad * 8 + 32];
      f32x4 z = {};
      z = __builtin_amdgcn_mfma_f32_16x16x32_bf16(aq0, bk0, z, 0, 0, 0);
      z = __builtin_amdgcn_mfma_f32_16x16x32_bf16(aq1, bk1, z, 0, 0, 0);
      s[nt] = z;
    }

    // mask: adj in {0,1} -> s *= adj reproduces (adj>0 ? s : 0.0)
    if (use_adj) {
#pragma unroll
      for (int nt = 0; nt < 4; ++nt)
#pragma unroll
        for (int r = 0; r < 4; ++r)
          s[nt][r] *= abase[(long)r * N_ + kt * 64 + nt * 16 + l16];
    }

    // exp2 (q pre-scaled by log2e; fixed max 0) + lane-partial row sums
#pragma unroll
    for (int nt = 0; nt < 4; ++nt)
#pragma unroll
      for (int r = 0; r < 4; ++r) {
        const float e = __builtin_amdgcn_exp2f(s[nt][r]);
        s[nt][r] = e;
        l_part[r] += e;
      }

    // P: C layout -> wave-private LDS panel -> A-operand layout
#pragma unroll
    for (int nt = 0; nt < 4; ++nt)
#pragma unroll
      for (int r = 0; r < 4; ++r)
        Ps[w][quad * 4 + r][nt * 16 + l16] = (bf16_t)s[nt][r];
    __builtin_amdgcn_s_waitcnt(0xC07F);   // lgkmcnt(0)

    bf16x8 ap0 = *(const bf16x8*)&Ps[w][l16][quad * 8];
    bf16x8 ap1 = *(const bf16x8*)&Ps[w][l16][quad * 8 + 32];
#pragma unroll
    for (int nt = 0; nt < 4; ++nt) {
      bf16x8 bv0 = *(const bf16x8*)&Vs[nt * 16 + l16][quad * 8];
      bf16x8 bv1 = *(const bf16x8*)&Vs[nt * 16 + l16][quad * 8 + 32];
      accO[nt] = __builtin_amdgcn_mfma_f32_16x16x32_bf16(ap0, bv0, accO[nt], 0, 0, 0);
      accO[nt] = __builtin_amdgcn_mfma_f32_16x16x32_bf16(ap1, bv1, accO[nt], 0, 0, 0);
    }
  }

#pragma unroll
  for (int o = 1; o < 16; o <<= 1)
#pragma unroll
    for (int r = 0; r < 4; ++r) l_part[r] += __shfl_xor(l_part[r], o, 64);
  float inv[4];
#pragma unroll
  for (int r = 0; r < 4; ++r) inv[r] = 1.0f / l_part[r];
#pragma unroll
  for (int r = 0; r < 4; ++r) {
    const long orow = (long)(b * N_ + q0 + w * 16 + quad * 4 + r) * D_ + h * DK_;
#pragma unroll
    for (int nt = 0; nt < 4; ++nt)
      ctx[orow + nt * 16 + l16] = (bf16_t)(accO[nt][r] * inv[r]);
  }
}

// ---------------------------------------------------------------------------------
extern "C" void kernel_launch(void* const* d_in, const int* in_sizes, int n_in,
                              void* d_out, int out_size, void* d_ws, size_t ws_size,
                              hipStream_t stream) {
  (void)in_sizes; (void)n_in; (void)out_size; (void)ws_size;
  const float* x    = (const float*)d_in[0];
  const float* adj  = (const float*)d_in[1];
  const float* W_w  = (const float*)d_in[2];
  const float* W_b  = (const float*)d_in[3];
  const float* ln_g = (const float*)d_in[4];
  const float* ln_b = (const float*)d_in[5];
  const float* Wq   = (const float*)d_in[6];
  const float* bq   = (const float*)d_in[7];
  const float* Wk   = (const float*)d_in[8];
  const float* bk   = (const float*)d_in[9];
  const float* Wv   = (const float*)d_in[10];
  const float* bv   = (const float*)d_in[11];
  const float* Wo   = (const float*)d_in[12];
  const float* bo   = (const float*)d_in[13];
  const float* gw   = (const float*)d_in[14];
  const float* gb   = (const float*)d_in[15];
  const int* use_adj = (const int*)d_in[16];

  char* ws = (char*)d_ws;
  size_t off = 0;
  auto alloc = [&](size_t bytes) -> void* {
    void* p = ws + off;
    off += (bytes + 255) & ~(size_t)255;
    return p;
  };
  bf16_t*  WtW   = (bf16_t*)alloc((size_t)D_ * D_ * 2);
  bf16_t*  WtQKV = (bf16_t*)alloc((size_t)3 * D_ * D_ * 2);
  bf16_t*  WtO   = (bf16_t*)alloc((size_t)D_ * D_ * 2);
  bf16_t*  xb    = (bf16_t*)alloc((size_t)BN_ * D_ * 2);
  bf16_t*  hB    = (bf16_t*)alloc((size_t)BN_ * D_ * 2);
  bf16_t*  qkB   = (bf16_t*)alloc((size_t)BN_ * 2 * D_ * 2);  // q|k, ld 1024
  bf16_t*  vTB   = (bf16_t*)alloc((size_t)BN_ * D_ * 2);      // per-head V^T
  bf16_t*  ctxB  = (bf16_t*)alloc((size_t)BN_ * D_ * 2);

  WPrep wp;
  wp.src[0] = W_w; wp.dst[0] = WtW;
  wp.src[1] = Wq;  wp.dst[1] = WtQKV;
  wp.src[2] = Wk;  wp.dst[2] = WtQKV + (size_t)D_ * D_;
  wp.src[3] = Wv;  wp.dst[3] = WtQKV + (size_t)2 * D_ * D_;
  wp.src[4] = Wo;  wp.dst[4] = WtO;
  k_prep<<<3328, 256, 0, stream>>>(x, xb, wp);

  // h-GEMM + LayerNorm fused (row-owning 32x512 tiles)
  k_gemm_row<0><<<BN_ / 32, 512, 0, stream>>>(xb, WtW, W_b, ln_g, ln_b, nullptr, hB);
  // q scale folds SCALE * log2(e) so attention can use raw v_exp_f32 (exp2)
  dim3 gqkv(BN_ / 128, 3 * D_ / 64);     // 64 x 24 (128x64 tiles, ~4 blocks/CU)
  k_gemm_qkv<<<gqkv, 256, 0, stream>>>(hB, WtQKV, bq, bk, bv,
                                       0.125f * LOG2E, qkB, vTB);
  k_attn<<<1024, 256, 0, stream>>>(qkB, vTB, adj, use_adj, ctxB);
  // O-GEMM + ReLU + gate fused -> final fp32 output
  k_gemm_row<1><<<BN_ / 32, 512, 0, stream>>>(ctxB, WtO, bo, x, gw, gb, d_out);
}

// Round 18
// 197.228 us; speedup vs baseline: 1.0396x; 1.0396x over previous
//
#include <hip/hip_runtime.h>
#include <stdint.h>

// MH_gate — R16: attn block->XCD remap for adj L2 reuse; QKV reverted to R10
// 128x128 (3rd submit; R16/R17 benches hit infra timeouts).
// adj arithmetic: each attn block reads 128KB of adj; 8 heads of the same
// (b,qt) read IDENTICAL rows. Old mapping (h in low bits) -> 8 sharers on 8
// different XCDs -> 128MB/iter refetched from L3. New mapping h=id>>7,
// qt=(id>>4)&7, b=id&15 (bijective): sharers differ by 128 = 0 mod 8 -> same
// XCD -> adj L3 traffic /8. Predicted: 202 -> ~193-197 if adj-BW-limited;
// null => attn latency-bound, plateau against the ~105us harness envelope.
// CONTRACT: float inputs fp32 storage (bf16-rounded values), out fp32,
// use_adj int32. Mask: adj in {0,1} -> s*adj. exp via exp2, log2e folded in q.
// History: R3 occ null, R4 dbuf null, R6 fusion null, R10 swizzle null,
// R15 QKV retile null. R9 instrumentation: kernel sum ~100us, env ~105us.

typedef __bf16 bf16_t;
typedef __bf16 bf16x8 __attribute__((ext_vector_type(8)));
typedef float  f32x4  __attribute__((ext_vector_type(4)));

#define B_   16
#define N_   512
#define D_   512
#define H_   8
#define DK_  64
#define BN_  8192
#define LOG2E 1.4426950408889634f

// ---- async global->LDS, 16B per lane --------------------------------------------
__device__ __forceinline__ void gl2lds16(const void* g, void* l) {
  __builtin_amdgcn_global_load_lds(
      (const __attribute__((address_space(1))) void*)g,
      (__attribute__((address_space(3))) void*)l, 16, 0, 0);
}

// ---- merged prep: x cast (blocks 0..2047), W^T (2048..3327) ----------------------
struct WPrep { const float* src[5]; bf16_t* dst[5]; };
__global__ __launch_bounds__(256) void k_prep(const float* __restrict__ x,
                                              bf16_t* __restrict__ xb,
                                              WPrep p) {
  __shared__ float tile[32][33];
  const int blk = blockIdx.x;
  const int t = threadIdx.x;
  if (blk < 2048) {               // x fp32 -> bf16 (lossless: bf16-rounded values)
    const long i = ((long)blk * 256 + t) * 8;
    float4 a = *(const float4*)&x[i];
    float4 b = *(const float4*)&x[i + 4];
    bf16x8 o;
    o[0] = (bf16_t)a.x; o[1] = (bf16_t)a.y; o[2] = (bf16_t)a.z; o[3] = (bf16_t)a.w;
    o[4] = (bf16_t)b.x; o[5] = (bf16_t)b.y; o[6] = (bf16_t)b.z; o[7] = (bf16_t)b.w;
    *(bf16x8*)&xb[i] = o;
  } else {                        // Wt[n][k] = bf16(W[k][n]), 5 weights
    const int r = blk - 2048;
    const int z = r >> 8, rem = r & 255;
    const float* W = p.src[z];
    bf16_t* Wt = p.dst[z];
    const int kb = (rem & 15) * 32, nb = (rem >> 4) * 32;
    const int tx = t & 31, ty = t >> 5;
#pragma unroll
    for (int i = ty; i < 32; i += 8)
      tile[i][tx] = W[(long)(kb + i) * D_ + nb + tx];
    __syncthreads();
#pragma unroll
    for (int i = ty; i < 32; i += 8)
      Wt[(long)(nb + i) * D_ + kb + tx] = (bf16_t)tile[tx][i];
  }
}

// Swizzle helpers (both-sides involution, proven neutral R10, kept for min-diff):
//   stage thread t: row = t>>2, phys 16B-slot = t&3 -> fetch global slot
//   (t&3) ^ ((t>>3)&3); read lane: slot = quad ^ ((l16>>1)&3).

// ---- row-owning 32x512 GEMM with fused row-wise epilogue -------------------------
// MODE 0: LN  — out bf16 = (v-mu)*rstd*g + b,  v = A@Bt^T + bias
// MODE 1: gate — h2 = relu(v); z = x.gw0 + h2.gw1 + gb; out fp32 = c*x+(1-c)*h2
template <int MODE>
__global__ __launch_bounds__(512) void k_gemm_row(const bf16_t* __restrict__ A,
                                                  const bf16_t* __restrict__ Bt,
                                                  const float* __restrict__ bias,
                                                  const float* __restrict__ p0,
                                                  const float* __restrict__ p1,
                                                  const float* __restrict__ p2,
                                                  void* __restrict__ outp) {
  __shared__ bf16_t As[2][32 * 32];
  __shared__ bf16_t Bs[2][512 * 32];
  __shared__ float red[8][32][2];
  __shared__ float rowc[32][2];
  const int t = threadIdx.x;
  const int w = t >> 6, lane = t & 63;
  const int quad = lane >> 4, l16 = lane & 15;
  const int m0 = blockIdx.x * 32;
  const int wn = w * 64;

  const int ea = t * 8;
  const int scol = (((t & 3) ^ ((t >> 3) & 3)) * 8);
  const bf16_t* agp = A + (long)(m0 + (t >> 2)) * 512 + scol;
  const bf16_t* bgp[4];
  int eb[4];
#pragma unroll
  for (int j = 0; j < 4; ++j) {
    eb[j] = j * 4096 + t * 8;
    bgp[j] = Bt + (long)(j * 128 + (t >> 2)) * 512 + scol;
  }

  const int csw = (quad ^ ((l16 >> 1) & 3)) * 8;

  f32x4 acc[2][4] = {};

  if (t < 128) gl2lds16(agp, &As[0][ea]);
#pragma unroll
  for (int j = 0; j < 4; ++j) gl2lds16(bgp[j], &Bs[0][eb[j]]);
  __syncthreads();

  int cur = 0;
  for (int k0 = 0; k0 < 512; k0 += 32) {
    const int nxt = cur ^ 1;
    if (k0 + 32 < 512) {
      if (t < 128) gl2lds16(agp + k0 + 32, &As[nxt][ea]);
#pragma unroll
      for (int j = 0; j < 4; ++j) gl2lds16(bgp[j] + k0 + 32, &Bs[nxt][eb[j]]);
    }
    bf16x8 af[2], bfr[4];
#pragma unroll
    for (int mi = 0; mi < 2; ++mi)
      af[mi] = *(const bf16x8*)&As[cur][(mi * 16 + l16) * 32 + csw];
#pragma unroll
    for (int ni = 0; ni < 4; ++ni)
      bfr[ni] = *(const bf16x8*)&Bs[cur][(wn + ni * 16 + l16) * 32 + csw];
#pragma unroll
    for (int mi = 0; mi < 2; ++mi)
#pragma unroll
      for (int ni = 0; ni < 4; ++ni)
        acc[mi][ni] = __builtin_amdgcn_mfma_f32_16x16x32_bf16(af[mi], bfr[ni],
                                                              acc[mi][ni], 0, 0, 0);
    __syncthreads();
    cur = nxt;
  }

  float bv[4];
#pragma unroll
  for (int ni = 0; ni < 4; ++ni) bv[ni] = bias[wn + ni * 16 + l16];

  if (MODE == 0) {
    // ---- LayerNorm epilogue ----
#pragma unroll
    for (int mi = 0; mi < 2; ++mi)
#pragma unroll
      for (int r = 0; r < 4; ++r) {
        float s1 = 0.f, s2 = 0.f;
#pragma unroll
        for (int ni = 0; ni < 4; ++ni) {
          const float v = acc[mi][ni][r] + bv[ni];
          s1 += v; s2 += v * v;
        }
#pragma unroll
        for (int o = 1; o < 16; o <<= 1) {
          s1 += __shfl_xor(s1, o, 64);
          s2 += __shfl_xor(s2, o, 64);
        }
        if (l16 == 0) {
          const int row = mi * 16 + quad * 4 + r;
          red[w][row][0] = s1; red[w][row][1] = s2;
        }
      }
    __syncthreads();
    if (t < 32) {
      float S1 = 0.f, S2 = 0.f;
#pragma unroll
      for (int wv = 0; wv < 8; ++wv) { S1 += red[wv][t][0]; S2 += red[wv][t][1]; }
      const float mu = S1 * (1.0f / 512.0f);
      const float var = S2 * (1.0f / 512.0f) - mu * mu;
      rowc[t][0] = mu;
      rowc[t][1] = rsqrtf(var + 1e-5f);
    }
    __syncthreads();
    float gv[4], b2[4];
#pragma unroll
    for (int ni = 0; ni < 4; ++ni) {
      gv[ni] = p0[wn + ni * 16 + l16];
      b2[ni] = p1[wn + ni * 16 + l16];
    }
#pragma unroll
    for (int mi = 0; mi < 2; ++mi)
#pragma unroll
      for (int r = 0; r < 4; ++r) {
        const int row = mi * 16 + quad * 4 + r;
        const float mu = rowc[row][0], rs = rowc[row][1];
#pragma unroll
        for (int ni = 0; ni < 4; ++ni) {
          const float v = acc[mi][ni][r] + bv[ni];
          ((bf16_t*)outp)[(long)(m0 + row) * 512 + wn + ni * 16 + l16] =
              (bf16_t)((v - mu) * rs * gv[ni] + b2[ni]);
        }
      }
  } else {
    // ---- ReLU + gate epilogue ----
    float g0[4], g1[4];
#pragma unroll
    for (int ni = 0; ni < 4; ++ni) {
      g0[ni] = p1[wn + ni * 16 + l16];
      g1[ni] = p1[512 + wn + ni * 16 + l16];
    }
    float xr[2][4][4];
#pragma unroll
    for (int mi = 0; mi < 2; ++mi)
#pragma unroll
      for (int r = 0; r < 4; ++r) {
        const int row = mi * 16 + quad * 4 + r;
#pragma unroll
        for (int ni = 0; ni < 4; ++ni)
          xr[mi][ni][r] = p0[(long)(m0 + row) * 512 + wn + ni * 16 + l16];
      }
#pragma unroll
    for (int mi = 0; mi < 2; ++mi)
#pragma unroll
      for (int r = 0; r < 4; ++r) {
        float px = 0.f, ph = 0.f;
#pragma unroll
        for (int ni = 0; ni < 4; ++ni) {
          const float h2 = fmaxf(acc[mi][ni][r] + bv[ni], 0.0f);
          px += xr[mi][ni][r] * g0[ni];
          ph += h2 * g1[ni];
        }
#pragma unroll
        for (int o = 1; o < 16; o <<= 1) {
          px += __shfl_xor(px, o, 64);
          ph += __shfl_xor(ph, o, 64);
        }
        if (l16 == 0) {
          const int row = mi * 16 + quad * 4 + r;
          red[w][row][0] = px; red[w][row][1] = ph;
        }
      }
    __syncthreads();
    if (t < 32) {
      float z = p2[0];
#pragma unroll
      for (int wv = 0; wv < 8; ++wv) z += red[wv][t][0] + red[wv][t][1];
      rowc[t][0] = 1.0f / (1.0f + __expf(-z));
    }
    __syncthreads();
#pragma unroll
    for (int mi = 0; mi < 2; ++mi)
#pragma unroll
      for (int r = 0; r < 4; ++r) {
        const int row = mi * 16 + quad * 4 + r;
        const float c = rowc[row][0];
#pragma unroll
        for (int ni = 0; ni < 4; ++ni) {
          const float h2 = fmaxf(acc[mi][ni][r] + bv[ni], 0.0f);
          ((float*)outp)[(long)(m0 + row) * 512 + wn + ni * 16 + l16] =
              c * xr[mi][ni][r] + (1.0f - c) * h2;
        }
      }
  }
}

// ---- 128x128 GEMM, QKV mode (R10 config, best measured) --------------------------
// seg<2 (q,k) -> bf16 qk buffer (ld 1024); seg==2 (v) -> vT[((b*8+h)*64+dk)*512+tok].
__global__ __launch_bounds__(256) void k_gemm_qkv(const bf16_t* __restrict__ A,
                                                  const bf16_t* __restrict__ Bt,
                                                  const float* __restrict__ b0,
                                                  const float* __restrict__ b1,
                                                  const float* __restrict__ b2,
                                                  float s0,
                                                  bf16_t* __restrict__ outp,
                                                  bf16_t* __restrict__ vtp) {
  __shared__ bf16_t As[2][128 * 32];
  __shared__ bf16_t Bs[2][128 * 32];
  const int t = threadIdx.x;
  const int m0 = blockIdx.x * 128;
  const int n0 = blockIdx.y * 128;
  const int w = t >> 6, lane = t & 63;
  const int quad = lane >> 4, l16 = lane & 15;
  const int wm = (w >> 1) * 64, wn = (w & 1) * 64;

  const int e0 = t * 8;
  const int r0 = t >> 2;
  const int scol = (((t & 3) ^ ((t >> 3) & 3)) * 8);   // pre-swizzled source col
  const bf16_t* agp0 = A + (long)(m0 + r0) * 512 + scol;
  const bf16_t* agp1 = agp0 + (long)64 * 512;          // rows+64: same swizzle bits
  const bf16_t* bgp0 = Bt + (long)(n0 + r0) * 512 + scol;
  const bf16_t* bgp1 = bgp0 + (long)64 * 512;

  const int csw = (quad ^ ((l16 >> 1) & 3)) * 8;       // swizzled read col

  f32x4 acc[4][4] = {};

  gl2lds16(agp0, &As[0][e0]);
  gl2lds16(agp1, &As[0][e0 + 2048]);
  gl2lds16(bgp0, &Bs[0][e0]);
  gl2lds16(bgp1, &Bs[0][e0 + 2048]);
  __syncthreads();

  int cur = 0;
  for (int k0 = 0; k0 < 512; k0 += 32) {
    const int nxt = cur ^ 1;
    if (k0 + 32 < 512) {
      gl2lds16(agp0 + k0 + 32, &As[nxt][e0]);
      gl2lds16(agp1 + k0 + 32, &As[nxt][e0 + 2048]);
      gl2lds16(bgp0 + k0 + 32, &Bs[nxt][e0]);
      gl2lds16(bgp1 + k0 + 32, &Bs[nxt][e0 + 2048]);
    }
    bf16x8 af[4], bfr[4];
#pragma unroll
    for (int i = 0; i < 4; ++i) {
      af[i]  = *(const bf16x8*)&As[cur][(wm + i * 16 + l16) * 32 + csw];
      bfr[i] = *(const bf16x8*)&Bs[cur][(wn + i * 16 + l16) * 32 + csw];
    }
#pragma unroll
    for (int mi = 0; mi < 4; ++mi)
#pragma unroll
      for (int ni = 0; ni < 4; ++ni)
        acc[mi][ni] = __builtin_amdgcn_mfma_f32_16x16x32_bf16(af[mi], bfr[ni],
                                                              acc[mi][ni], 0, 0, 0);
    __syncthreads();
    cur = nxt;
  }

  const int seg = n0 >> 9;
  const float* bias = (seg == 0) ? b0 : (seg == 1) ? b1 : b2;
  const float scale = (seg == 0) ? s0 : 1.0f;
#pragma unroll
  for (int ni = 0; ni < 4; ++ni) {
    const int n = n0 + wn + ni * 16 + l16;
    const float bvv = bias[n & 511];
#pragma unroll
    for (int mi = 0; mi < 4; ++mi)
#pragma unroll
      for (int r = 0; r < 4; ++r) {
        const long m = m0 + wm + mi * 16 + quad * 4 + r;
        const float v = (acc[mi][ni][r] + bvv) * scale;
        if (seg < 2) {
          outp[m * 1024 + n] = (bf16_t)v;
        } else {
          const int tok = (int)m & 511, bb = (int)(m >> 9);
          const int hh = (n >> 6) & 7, dk = n & 63;
          vtp[(((long)bb * 8 + hh) * 64 + dk) * 512 + tok] = (bf16_t)v;
        }
      }
  }
}

// ---- MFMA flash attention: 64 q-rows/block, 1024 blocks ---------------------------
// R16 remap: h = id>>7, qt = (id>>4)&7, b = id&15  (bijective over 1024).
// The 8 blocks sharing (b,qt) — which read IDENTICAL adj rows — have ids
// differing by 128 = 0 mod 8 -> same XCD -> adj fetched once per group.
__global__ __launch_bounds__(256) void k_attn(const bf16_t* __restrict__ qk,
                                              const bf16_t* __restrict__ vT,
                                              const float* __restrict__ adj,
                                              const int* __restrict__ use_adj_p,
                                              bf16_t* __restrict__ ctx) {
  __shared__ bf16_t Ks[64][72];
  __shared__ bf16_t Vs[64][72];
  __shared__ bf16_t Ps[4][16][72];
  const int t = threadIdx.x;
  const int w = t >> 6, lane = t & 63;
  const int quad = lane >> 4, l16 = lane & 15;
  const int h  = blockIdx.x >> 7;          // high bits: same (b,qt) -> same XCD
  const int qt = (blockIdx.x >> 4) & 7;
  const int b  = blockIdx.x & 15;
  const int bh = b * 8 + h;
  const int q0 = qt * 64;
  const int use_adj = use_adj_p[0];

  const long qoff = (long)(b * N_ + q0 + w * 16 + l16) * 1024 + h * DK_ + quad * 8;
  const bf16x8 aq0 = *(const bf16x8*)&qk[qoff];
  const bf16x8 aq1 = *(const bf16x8*)&qk[qoff + 32];

  const int sr = t >> 2, sc = (t & 3) * 16;
  const bf16_t* kbase  = qk + (long)b * N_ * 1024 + 512 + h * DK_;
  const bf16_t* vtbase = vT + (long)bh * DK_ * N_;
  const float*  abase  = adj + ((long)b * N_ + q0 + w * 16 + quad * 4) * N_;

  f32x4 accO[4] = {};
  float l_part[4] = {0.f, 0.f, 0.f, 0.f};

  for (int kt = 0; kt < 8; ++kt) {
    __syncthreads();
    {
      const bf16_t* ksrc = kbase + (long)(kt * 64 + sr) * 1024 + sc;
      *(uint4*)&Ks[sr][sc]     = *(const uint4*)ksrc;
      *(uint4*)&Ks[sr][sc + 8] = *(const uint4*)(ksrc + 8);
      const bf16_t* vsrc = vtbase + (long)sr * N_ + kt * 64 + sc;
      *(uint4*)&Vs[sr][sc]     = *(const uint4*)vsrc;
      *(uint4*)&Vs[sr][sc + 8] = *(const uint4*)(vsrc + 8);
    }
    __syncthreads();

    // S = Q K^T (16 x 64)
    f32x4 s[4];
#pragma unroll
    for (int nt = 0; nt < 4; ++nt) {
      bf16x8 bk0 = *(const bf16x8*)&Ks[nt * 16 + l16][quad * 8];
      bf16x8 bk1 = *(const bf16x8*)&Ks[nt * 16 + l16][quad * 8 + 32];
      f32x4 z = {};
      z = __builtin_amdgcn_mfma_f32_16x16x32_bf16(aq0, bk0, z, 0, 0, 0);
      z = __builtin_amdgcn_mfma_f32_16x16x32_bf16(aq1, bk1, z, 0, 0, 0);
      s[nt] = z;
    }

    // mask: adj in {0,1} -> s *= adj reproduces (adj>0 ? s : 0.0)
    if (use_adj) {
#pragma unroll
      for (int nt = 0; nt < 4; ++nt)
#pragma unroll
        for (int r = 0; r < 4; ++r)
          s[nt][r] *= abase[(long)r * N_ + kt * 64 + nt * 16 + l16];
    }

    // exp2 (q pre-scaled by log2e; fixed max 0) + lane-partial row sums
#pragma unroll
    for (int nt = 0; nt < 4; ++nt)
#pragma unroll
      for (int r = 0; r < 4; ++r) {
        const float e = __builtin_amdgcn_exp2f(s[nt][r]);
        s[nt][r] = e;
        l_part[r] += e;
      }

    // P: C layout -> wave-private LDS panel -> A-operand layout
#pragma unroll
    for (int nt = 0; nt < 4; ++nt)
#pragma unroll
      for (int r = 0; r < 4; ++r)
        Ps[w][quad * 4 + r][nt * 16 + l16] = (bf16_t)s[nt][r];
    __builtin_amdgcn_s_waitcnt(0xC07F);   // lgkmcnt(0)

    bf16x8 ap0 = *(const bf16x8*)&Ps[w][l16][quad * 8];
    bf16x8 ap1 = *(const bf16x8*)&Ps[w][l16][quad * 8 + 32];
#pragma unroll
    for (int nt = 0; nt < 4; ++nt) {
      bf16x8 bv0 = *(const bf16x8*)&Vs[nt * 16 + l16][quad * 8];
      bf16x8 bv1 = *(const bf16x8*)&Vs[nt * 16 + l16][quad * 8 + 32];
      accO[nt] = __builtin_amdgcn_mfma_f32_16x16x32_bf16(ap0, bv0, accO[nt], 0, 0, 0);
      accO[nt] = __builtin_amdgcn_mfma_f32_16x16x32_bf16(ap1, bv1, accO[nt], 0, 0, 0);
    }
  }

#pragma unroll
  for (int o = 1; o < 16; o <<= 1)
#pragma unroll
    for (int r = 0; r < 4; ++r) l_part[r] += __shfl_xor(l_part[r], o, 64);
  float inv[4];
#pragma unroll
  for (int r = 0; r < 4; ++r) inv[r] = 1.0f / l_part[r];
#pragma unroll
  for (int r = 0; r < 4; ++r) {
    const long orow = (long)(b * N_ + q0 + w * 16 + quad * 4 + r) * D_ + h * DK_;
#pragma unroll
    for (int nt = 0; nt < 4; ++nt)
      ctx[orow + nt * 16 + l16] = (bf16_t)(accO[nt][r] * inv[r]);
  }
}

// ---------------------------------------------------------------------------------
extern "C" void kernel_launch(void* const* d_in, const int* in_sizes, int n_in,
                              void* d_out, int out_size, void* d_ws, size_t ws_size,
                              hipStream_t stream) {
  (void)in_sizes; (void)n_in; (void)out_size; (void)ws_size;
  const float* x    = (const float*)d_in[0];
  const float* adj  = (const float*)d_in[1];
  const float* W_w  = (const float*)d_in[2];
  const float* W_b  = (const float*)d_in[3];
  const float* ln_g = (const float*)d_in[4];
  const float* ln_b = (const float*)d_in[5];
  const float* Wq   = (const float*)d_in[6];
  const float* bq   = (const float*)d_in[7];
  const float* Wk   = (const float*)d_in[8];
  const float* bk   = (const float*)d_in[9];
  const float* Wv   = (const float*)d_in[10];
  const float* bv   = (const float*)d_in[11];
  const float* Wo   = (const float*)d_in[12];
  const float* bo   = (const float*)d_in[13];
  const float* gw   = (const float*)d_in[14];
  const float* gb   = (const float*)d_in[15];
  const int* use_adj = (const int*)d_in[16];

  char* ws = (char*)d_ws;
  size_t off = 0;
  auto alloc = [&](size_t bytes) -> void* {
    void* p = ws + off;
    off += (bytes + 255) & ~(size_t)255;
    return p;
  };
  bf16_t*  WtW   = (bf16_t*)alloc((size_t)D_ * D_ * 2);
  bf16_t*  WtQKV = (bf16_t*)alloc((size_t)3 * D_ * D_ * 2);
  bf16_t*  WtO   = (bf16_t*)alloc((size_t)D_ * D_ * 2);
  bf16_t*  xb    = (bf16_t*)alloc((size_t)BN_ * D_ * 2);
  bf16_t*  hB    = (bf16_t*)alloc((size_t)BN_ * D_ * 2);
  bf16_t*  qkB   = (bf16_t*)alloc((size_t)BN_ * 2 * D_ * 2);  // q|k, ld 1024
  bf16_t*  vTB   = (bf16_t*)alloc((size_t)BN_ * D_ * 2);      // per-head V^T
  bf16_t*  ctxB  = (bf16_t*)alloc((size_t)BN_ * D_ * 2);

  WPrep wp;
  wp.src[0] = W_w; wp.dst[0] = WtW;
  wp.src[1] = Wq;  wp.dst[1] = WtQKV;
  wp.src[2] = Wk;  wp.dst[2] = WtQKV + (size_t)D_ * D_;
  wp.src[3] = Wv;  wp.dst[3] = WtQKV + (size_t)2 * D_ * D_;
  wp.src[4] = Wo;  wp.dst[4] = WtO;
  k_prep<<<3328, 256, 0, stream>>>(x, xb, wp);

  // h-GEMM + LayerNorm fused (row-owning 32x512 tiles)
  k_gemm_row<0><<<BN_ / 32, 512, 0, stream>>>(xb, WtW, W_b, ln_g, ln_b, nullptr, hB);
  // q scale folds SCALE * log2(e) so attention can use raw v_exp_f32 (exp2)
  dim3 gqkv(BN_ / 128, 3 * D_ / 128);    // 64 x 12 (128x128 tiles, R10 config)
  k_gemm_qkv<<<gqkv, 256, 0, stream>>>(hB, WtQKV, bq, bk, bv,
                                       0.125f * LOG2E, qkB, vTB);
  k_attn<<<1024, 256, 0, stream>>>(qkB, vTB, adj, use_adj, ctxB);
  // O-GEMM + ReLU + gate fused -> final fp32 output
  k_gemm_row<1><<<BN_ / 32, 512, 0, stream>>>(ctxB, WtO, bo, x, gw, gb, d_out);
}

// Round 20
// 196.149 us; speedup vs baseline: 1.0453x; 1.0055x over previous
//
#include <hip/hip_runtime.h>
#include <stdint.h>

// MH_gate — R19: fold x fp32->bf16 cast into h-GEMM A-staging (reg-staged A
// tile with inline cvt + swizzled ds_write); prep shrinks to W^T only
// (1280 blocks). (2nd submit; R19 bench hit infra timeout.) Keeps R16's
// proven attn XCD remap (202.0 -> 197.2, the session's one real win:
// post-remap adj working set 2MB/XCD fits L2).
// Traffic: -25MB prep (x read + xb write) - 8.4MB xb re-read + 8.4MB fp32
// A-read = net -17MB (~-3us) + ~-2us prep execution. Predicted 197.2 ->
// ~191-194. Null => latency/envelope plateau, declare next round.
// CONTRACT: float inputs fp32 storage (bf16-rounded values), out fp32,
// use_adj int32. Mask: adj in {0,1} -> s*adj. exp via exp2, log2e folded in q.
// History: R3 occ null, R4 dbuf null, R6 fusion null, R10 swizzle null,
// R15 QKV retile null, R16 adj remap WIN (-4.8us). Envelope ~105us immutable.

typedef __bf16 bf16_t;
typedef __bf16 bf16x8 __attribute__((ext_vector_type(8)));
typedef float  f32x4  __attribute__((ext_vector_type(4)));

#define B_   16
#define N_   512
#define D_   512
#define H_   8
#define DK_  64
#define BN_  8192
#define LOG2E 1.4426950408889634f

// ---- async global->LDS, 16B per lane --------------------------------------------
__device__ __forceinline__ void gl2lds16(const void* g, void* l) {
  __builtin_amdgcn_global_load_lds(
      (const __attribute__((address_space(1))) void*)g,
      (__attribute__((address_space(3))) void*)l, 16, 0, 0);
}

// ---- prep: W^T only now (x-cast moved into k_gemm_row<0>) ------------------------
struct WPrep { const float* src[5]; bf16_t* dst[5]; };
__global__ __launch_bounds__(256) void k_prep(WPrep p) {
  __shared__ float tile[32][33];
  const int r = blockIdx.x;
  const int t = threadIdx.x;
  const int z = r >> 8, rem = r & 255;
  const float* W = p.src[z];
  bf16_t* Wt = p.dst[z];
  const int kb = (rem & 15) * 32, nb = (rem >> 4) * 32;
  const int tx = t & 31, ty = t >> 5;
#pragma unroll
  for (int i = ty; i < 32; i += 8)
    tile[i][tx] = W[(long)(kb + i) * D_ + nb + tx];
  __syncthreads();
#pragma unroll
  for (int i = ty; i < 32; i += 8)
    Wt[(long)(nb + i) * D_ + kb + tx] = (bf16_t)tile[tx][i];
}

// Swizzle helpers (both-sides involution, neutral-measured R10, kept):
//   stage thread t: row = t>>2, phys 16B-slot = t&3 -> fetch source slot
//   (t&3) ^ ((t>>3)&3); read lane: slot = quad ^ ((l16>>1)&3).

// ---- row-owning 32x512 GEMM with fused row-wise epilogue -------------------------
// MODE 0: A from fp32 Af (inline cast, reg-staged A tile); LN epilogue -> bf16.
// MODE 1: A from bf16 (global_load_lds); ReLU+gate epilogue -> fp32 out.
template <int MODE>
__global__ __launch_bounds__(512) void k_gemm_row(const bf16_t* __restrict__ A,
                                                  const float* __restrict__ Af,
                                                  const bf16_t* __restrict__ Bt,
                                                  const float* __restrict__ bias,
                                                  const float* __restrict__ p0,
                                                  const float* __restrict__ p1,
                                                  const float* __restrict__ p2,
                                                  void* __restrict__ outp) {
  __shared__ bf16_t As[2][32 * 32];
  __shared__ bf16_t Bs[2][512 * 32];
  __shared__ float red[8][32][2];
  __shared__ float rowc[32][2];
  const int t = threadIdx.x;
  const int w = t >> 6, lane = t & 63;
  const int quad = lane >> 4, l16 = lane & 15;
  const int m0 = blockIdx.x * 32;
  const int wn = w * 64;

  const int ea = t * 8;
  const int scolE = (((t & 3) ^ ((t >> 3) & 3)) * 8);   // swizzled source slot (elems)
  const float*  axp = Af + (long)(m0 + (t >> 2)) * 512 + scolE;   // MODE 0
  const bf16_t* agp = A  + (long)(m0 + (t >> 2)) * 512 + scolE;   // MODE 1
  const bf16_t* bgp[4];
  int eb[4];
#pragma unroll
  for (int j = 0; j < 4; ++j) {
    eb[j] = j * 4096 + t * 8;
    bgp[j] = Bt + (long)(j * 128 + (t >> 2)) * 512 + scolE;
  }

  const int csw = (quad ^ ((l16 >> 1) & 3)) * 8;

  f32x4 acc[2][4] = {};

  // A-tile staging: MODE 0 = fp32 load + inline bf16 cast + swizzled ds_write;
  // MODE 1 = async global_load_lds (bf16 source).
  auto stageA = [&](int k0, int buf) {
    if (t < 128) {
      if (MODE == 0) {
        float4 a = *(const float4*)&axp[k0];
        float4 b = *(const float4*)&axp[k0 + 4];
        bf16x8 o;
        o[0] = (bf16_t)a.x; o[1] = (bf16_t)a.y; o[2] = (bf16_t)a.z; o[3] = (bf16_t)a.w;
        o[4] = (bf16_t)b.x; o[5] = (bf16_t)b.y; o[6] = (bf16_t)b.z; o[7] = (bf16_t)b.w;
        *(bf16x8*)&As[buf][ea] = o;
      } else {
        gl2lds16(agp + k0, &As[buf][ea]);
      }
    }
  };

  stageA(0, 0);
#pragma unroll
  for (int j = 0; j < 4; ++j) gl2lds16(bgp[j], &Bs[0][eb[j]]);
  __syncthreads();

  int cur = 0;
  for (int k0 = 0; k0 < 512; k0 += 32) {
    const int nxt = cur ^ 1;
    if (k0 + 32 < 512) {
      stageA(k0 + 32, nxt);
#pragma unroll
      for (int j = 0; j < 4; ++j) gl2lds16(bgp[j] + k0 + 32, &Bs[nxt][eb[j]]);
    }
    bf16x8 af[2], bfr[4];
#pragma unroll
    for (int mi = 0; mi < 2; ++mi)
      af[mi] = *(const bf16x8*)&As[cur][(mi * 16 + l16) * 32 + csw];
#pragma unroll
    for (int ni = 0; ni < 4; ++ni)
      bfr[ni] = *(const bf16x8*)&Bs[cur][(wn + ni * 16 + l16) * 32 + csw];
#pragma unroll
    for (int mi = 0; mi < 2; ++mi)
#pragma unroll
      for (int ni = 0; ni < 4; ++ni)
        acc[mi][ni] = __builtin_amdgcn_mfma_f32_16x16x32_bf16(af[mi], bfr[ni],
                                                              acc[mi][ni], 0, 0, 0);
    __syncthreads();
    cur = nxt;
  }

  float bv[4];
#pragma unroll
  for (int ni = 0; ni < 4; ++ni) bv[ni] = bias[wn + ni * 16 + l16];

  if (MODE == 0) {
    // ---- LayerNorm epilogue ----
#pragma unroll
    for (int mi = 0; mi < 2; ++mi)
#pragma unroll
      for (int r = 0; r < 4; ++r) {
        float s1 = 0.f, s2 = 0.f;
#pragma unroll
        for (int ni = 0; ni < 4; ++ni) {
          const float v = acc[mi][ni][r] + bv[ni];
          s1 += v; s2 += v * v;
        }
#pragma unroll
        for (int o = 1; o < 16; o <<= 1) {
          s1 += __shfl_xor(s1, o, 64);
          s2 += __shfl_xor(s2, o, 64);
        }
        if (l16 == 0) {
          const int row = mi * 16 + quad * 4 + r;
          red[w][row][0] = s1; red[w][row][1] = s2;
        }
      }
    __syncthreads();
    if (t < 32) {
      float S1 = 0.f, S2 = 0.f;
#pragma unroll
      for (int wv = 0; wv < 8; ++wv) { S1 += red[wv][t][0]; S2 += red[wv][t][1]; }
      const float mu = S1 * (1.0f / 512.0f);
      const float var = S2 * (1.0f / 512.0f) - mu * mu;
      rowc[t][0] = mu;
      rowc[t][1] = rsqrtf(var + 1e-5f);
    }
    __syncthreads();
    float gv[4], b2[4];
#pragma unroll
    for (int ni = 0; ni < 4; ++ni) {
      gv[ni] = p0[wn + ni * 16 + l16];
      b2[ni] = p1[wn + ni * 16 + l16];
    }
#pragma unroll
    for (int mi = 0; mi < 2; ++mi)
#pragma unroll
      for (int r = 0; r < 4; ++r) {
        const int row = mi * 16 + quad * 4 + r;
        const float mu = rowc[row][0], rs = rowc[row][1];
#pragma unroll
        for (int ni = 0; ni < 4; ++ni) {
          const float v = acc[mi][ni][r] + bv[ni];
          ((bf16_t*)outp)[(long)(m0 + row) * 512 + wn + ni * 16 + l16] =
              (bf16_t)((v - mu) * rs * gv[ni] + b2[ni]);
        }
      }
  } else {
    // ---- ReLU + gate epilogue ----
    float g0[4], g1[4];
#pragma unroll
    for (int ni = 0; ni < 4; ++ni) {
      g0[ni] = p1[wn + ni * 16 + l16];
      g1[ni] = p1[512 + wn + ni * 16 + l16];
    }
    float xr[2][4][4];
#pragma unroll
    for (int mi = 0; mi < 2; ++mi)
#pragma unroll
      for (int r = 0; r < 4; ++r) {
        const int row = mi * 16 + quad * 4 + r;
#pragma unroll
        for (int ni = 0; ni < 4; ++ni)
          xr[mi][ni][r] = p0[(long)(m0 + row) * 512 + wn + ni * 16 + l16];
      }
#pragma unroll
    for (int mi = 0; mi < 2; ++mi)
#pragma unroll
      for (int r = 0; r < 4; ++r) {
        float px = 0.f, ph = 0.f;
#pragma unroll
        for (int ni = 0; ni < 4; ++ni) {
          const float h2 = fmaxf(acc[mi][ni][r] + bv[ni], 0.0f);
          px += xr[mi][ni][r] * g0[ni];
          ph += h2 * g1[ni];
        }
#pragma unroll
        for (int o = 1; o < 16; o <<= 1) {
          px += __shfl_xor(px, o, 64);
          ph += __shfl_xor(ph, o, 64);
        }
        if (l16 == 0) {
          const int row = mi * 16 + quad * 4 + r;
          red[w][row][0] = px; red[w][row][1] = ph;
        }
      }
    __syncthreads();
    if (t < 32) {
      float z = p2[0];
#pragma unroll
      for (int wv = 0; wv < 8; ++wv) z += red[wv][t][0] + red[wv][t][1];
      rowc[t][0] = 1.0f / (1.0f + __expf(-z));
    }
    __syncthreads();
#pragma unroll
    for (int mi = 0; mi < 2; ++mi)
#pragma unroll
      for (int r = 0; r < 4; ++r) {
        const int row = mi * 16 + quad * 4 + r;
        const float c = rowc[row][0];
#pragma unroll
        for (int ni = 0; ni < 4; ++ni) {
          const float h2 = fmaxf(acc[mi][ni][r] + bv[ni], 0.0f);
          ((float*)outp)[(long)(m0 + row) * 512 + wn + ni * 16 + l16] =
              c * xr[mi][ni][r] + (1.0f - c) * h2;
        }
      }
  }
}

// ---- 128x128 GEMM, QKV mode (R10 config, best measured) --------------------------
// seg<2 (q,k) -> bf16 qk buffer (ld 1024); seg==2 (v) -> vT[((b*8+h)*64+dk)*512+tok].
__global__ __launch_bounds__(256) void k_gemm_qkv(const bf16_t* __restrict__ A,
                                                  const bf16_t* __restrict__ Bt,
                                                  const float* __restrict__ b0,
                                                  const float* __restrict__ b1,
                                                  const float* __restrict__ b2,
                                                  float s0,
                                                  bf16_t* __restrict__ outp,
                                                  bf16_t* __restrict__ vtp) {
  __shared__ bf16_t As[2][128 * 32];
  __shared__ bf16_t Bs[2][128 * 32];
  const int t = threadIdx.x;
  const int m0 = blockIdx.x * 128;
  const int n0 = blockIdx.y * 128;
  const int w = t >> 6, lane = t & 63;
  const int quad = lane >> 4, l16 = lane & 15;
  const int wm = (w >> 1) * 64, wn = (w & 1) * 64;

  const int e0 = t * 8;
  const int r0 = t >> 2;
  const int scol = (((t & 3) ^ ((t >> 3) & 3)) * 8);   // pre-swizzled source col
  const bf16_t* agp0 = A + (long)(m0 + r0) * 512 + scol;
  const bf16_t* agp1 = agp0 + (long)64 * 512;          // rows+64: same swizzle bits
  const bf16_t* bgp0 = Bt + (long)(n0 + r0) * 512 + scol;
  const bf16_t* bgp1 = bgp0 + (long)64 * 512;

  const int csw = (quad ^ ((l16 >> 1) & 3)) * 8;       // swizzled read col

  f32x4 acc[4][4] = {};

  gl2lds16(agp0, &As[0][e0]);
  gl2lds16(agp1, &As[0][e0 + 2048]);
  gl2lds16(bgp0, &Bs[0][e0]);
  gl2lds16(bgp1, &Bs[0][e0 + 2048]);
  __syncthreads();

  int cur = 0;
  for (int k0 = 0; k0 < 512; k0 += 32) {
    const int nxt = cur ^ 1;
    if (k0 + 32 < 512) {
      gl2lds16(agp0 + k0 + 32, &As[nxt][e0]);
      gl2lds16(agp1 + k0 + 32, &As[nxt][e0 + 2048]);
      gl2lds16(bgp0 + k0 + 32, &Bs[nxt][e0]);
      gl2lds16(bgp1 + k0 + 32, &Bs[nxt][e0 + 2048]);
    }
    bf16x8 af[4], bfr[4];
#pragma unroll
    for (int i = 0; i < 4; ++i) {
      af[i]  = *(const bf16x8*)&As[cur][(wm + i * 16 + l16) * 32 + csw];
      bfr[i] = *(const bf16x8*)&Bs[cur][(wn + i * 16 + l16) * 32 + csw];
    }
#pragma unroll
    for (int mi = 0; mi < 4; ++mi)
#pragma unroll
      for (int ni = 0; ni < 4; ++ni)
        acc[mi][ni] = __builtin_amdgcn_mfma_f32_16x16x32_bf16(af[mi], bfr[ni],
                                                              acc[mi][ni], 0, 0, 0);
    __syncthreads();
    cur = nxt;
  }

  const int seg = n0 >> 9;
  const float* bias = (seg == 0) ? b0 : (seg == 1) ? b1 : b2;
  const float scale = (seg == 0) ? s0 : 1.0f;
#pragma unroll
  for (int ni = 0; ni < 4; ++ni) {
    const int n = n0 + wn + ni * 16 + l16;
    const float bvv = bias[n & 511];
#pragma unroll
    for (int mi = 0; mi < 4; ++mi)
#pragma unroll
      for (int r = 0; r < 4; ++r) {
        const long m = m0 + wm + mi * 16 + quad * 4 + r;
        const float v = (acc[mi][ni][r] + bvv) * scale;
        if (seg < 2) {
          outp[m * 1024 + n] = (bf16_t)v;
        } else {
          const int tok = (int)m & 511, bb = (int)(m >> 9);
          const int hh = (n >> 6) & 7, dk = n & 63;
          vtp[(((long)bb * 8 + hh) * 64 + dk) * 512 + tok] = (bf16_t)v;
        }
      }
  }
}

// ---- MFMA flash attention: 64 q-rows/block, 1024 blocks ---------------------------
// R16 remap (measured WIN): h = id>>7, qt = (id>>4)&7, b = id&15 (bijective).
// The 8 blocks sharing (b,qt) — identical adj rows — land on the same XCD.
__global__ __launch_bounds__(256) void k_attn(const bf16_t* __restrict__ qk,
                                              const bf16_t* __restrict__ vT,
                                              const float* __restrict__ adj,
                                              const int* __restrict__ use_adj_p,
                                              bf16_t* __restrict__ ctx) {
  __shared__ bf16_t Ks[64][72];
  __shared__ bf16_t Vs[64][72];
  __shared__ bf16_t Ps[4][16][72];
  const int t = threadIdx.x;
  const int w = t >> 6, lane = t & 63;
  const int quad = lane >> 4, l16 = lane & 15;
  const int h  = blockIdx.x >> 7;          // high bits: same (b,qt) -> same XCD
  const int qt = (blockIdx.x >> 4) & 7;
  const int b  = blockIdx.x & 15;
  const int bh = b * 8 + h;
  const int q0 = qt * 64;
  const int use_adj = use_adj_p[0];

  const long qoff = (long)(b * N_ + q0 + w * 16 + l16) * 1024 + h * DK_ + quad * 8;
  const bf16x8 aq0 = *(const bf16x8*)&qk[qoff];
  const bf16x8 aq1 = *(const bf16x8*)&qk[qoff + 32];

  const int sr = t >> 2, sc = (t & 3) * 16;
  const bf16_t* kbase  = qk + (long)b * N_ * 1024 + 512 + h * DK_;
  const bf16_t* vtbase = vT + (long)bh * DK_ * N_;
  const float*  abase  = adj + ((long)b * N_ + q0 + w * 16 + quad * 4) * N_;

  f32x4 accO[4] = {};
  float l_part[4] = {0.f, 0.f, 0.f, 0.f};

  for (int kt = 0; kt < 8; ++kt) {
    __syncthreads();
    {
      const bf16_t* ksrc = kbase + (long)(kt * 64 + sr) * 1024 + sc;
      *(uint4*)&Ks[sr][sc]     = *(const uint4*)ksrc;
      *(uint4*)&Ks[sr][sc + 8] = *(const uint4*)(ksrc + 8);
      const bf16_t* vsrc = vtbase + (long)sr * N_ + kt * 64 + sc;
      *(uint4*)&Vs[sr][sc]     = *(const uint4*)vsrc;
      *(uint4*)&Vs[sr][sc + 8] = *(const uint4*)(vsrc + 8);
    }
    __syncthreads();

    // S = Q K^T (16 x 64)
    f32x4 s[4];
#pragma unroll
    for (int nt = 0; nt < 4; ++nt) {
      bf16x8 bk0 = *(const bf16x8*)&Ks[nt * 16 + l16][quad * 8];
      bf16x8 bk1 = *(const bf16x8*)&Ks[nt * 16 + l16][quad * 8 + 32];
      f32x4 z = {};
      z = __builtin_amdgcn_mfma_f32_16x16x32_bf16(aq0, bk0, z, 0, 0, 0);
      z = __builtin_amdgcn_mfma_f32_16x16x32_bf16(aq1, bk1, z, 0, 0, 0);
      s[nt] = z;
    }

    // mask: adj in {0,1} -> s *= adj reproduces (adj>0 ? s : 0.0)
    if (use_adj) {
#pragma unroll
      for (int nt = 0; nt < 4; ++nt)
#pragma unroll
        for (int r = 0; r < 4; ++r)
          s[nt][r] *= abase[(long)r * N_ + kt * 64 + nt * 16 + l16];
    }

    // exp2 (q pre-scaled by log2e; fixed max 0) + lane-partial row sums
#pragma unroll
    for (int nt = 0; nt < 4; ++nt)
#pragma unroll
      for (int r = 0; r < 4; ++r) {
        const float e = __builtin_amdgcn_exp2f(s[nt][r]);
        s[nt][r] = e;
        l_part[r] += e;
      }

    // P: C layout -> wave-private LDS panel -> A-operand layout
#pragma unroll
    for (int nt = 0; nt < 4; ++nt)
#pragma unroll
      for (int r = 0; r < 4; ++r)
        Ps[w][quad * 4 + r][nt * 16 + l16] = (bf16_t)s[nt][r];
    __builtin_amdgcn_s_waitcnt(0xC07F);   // lgkmcnt(0)

    bf16x8 ap0 = *(const bf16x8*)&Ps[w][l16][quad * 8];
    bf16x8 ap1 = *(const bf16x8*)&Ps[w][l16][quad * 8 + 32];
#pragma unroll
    for (int nt = 0; nt < 4; ++nt) {
      bf16x8 bv0 = *(const bf16x8*)&Vs[nt * 16 + l16][quad * 8];
      bf16x8 bv1 = *(const bf16x8*)&Vs[nt * 16 + l16][quad * 8 + 32];
      accO[nt] = __builtin_amdgcn_mfma_f32_16x16x32_bf16(ap0, bv0, accO[nt], 0, 0, 0);
      accO[nt] = __builtin_amdgcn_mfma_f32_16x16x32_bf16(ap1, bv1, accO[nt], 0, 0, 0);
    }
  }

#pragma unroll
  for (int o = 1; o < 16; o <<= 1)
#pragma unroll
    for (int r = 0; r < 4; ++r) l_part[r] += __shfl_xor(l_part[r], o, 64);
  float inv[4];
#pragma unroll
  for (int r = 0; r < 4; ++r) inv[r] = 1.0f / l_part[r];
#pragma unroll
  for (int r = 0; r < 4; ++r) {
    const long orow = (long)(b * N_ + q0 + w * 16 + quad * 4 + r) * D_ + h * DK_;
#pragma unroll
    for (int nt = 0; nt < 4; ++nt)
      ctx[orow + nt * 16 + l16] = (bf16_t)(accO[nt][r] * inv[r]);
  }
}

// ---------------------------------------------------------------------------------
extern "C" void kernel_launch(void* const* d_in, const int* in_sizes, int n_in,
                              void* d_out, int out_size, void* d_ws, size_t ws_size,
                              hipStream_t stream) {
  (void)in_sizes; (void)n_in; (void)out_size; (void)ws_size;
  const float* x    = (const float*)d_in[0];
  const float* adj  = (const float*)d_in[1];
  const float* W_w  = (const float*)d_in[2];
  const float* W_b  = (const float*)d_in[3];
  const float* ln_g = (const float*)d_in[4];
  const float* ln_b = (const float*)d_in[5];
  const float* Wq   = (const float*)d_in[6];
  const float* bq   = (const float*)d_in[7];
  const float* Wk   = (const float*)d_in[8];
  const float* bk   = (const float*)d_in[9];
  const float* Wv   = (const float*)d_in[10];
  const float* bv   = (const float*)d_in[11];
  const float* Wo   = (const float*)d_in[12];
  const float* bo   = (const float*)d_in[13];
  const float* gw   = (const float*)d_in[14];
  const float* gb   = (const float*)d_in[15];
  const int* use_adj = (const int*)d_in[16];

  char* ws = (char*)d_ws;
  size_t off = 0;
  auto alloc = [&](size_t bytes) -> void* {
    void* p = ws + off;
    off += (bytes + 255) & ~(size_t)255;
    return p;
  };
  bf16_t*  WtW   = (bf16_t*)alloc((size_t)D_ * D_ * 2);
  bf16_t*  WtQKV = (bf16_t*)alloc((size_t)3 * D_ * D_ * 2);
  bf16_t*  WtO   = (bf16_t*)alloc((size_t)D_ * D_ * 2);
  bf16_t*  hB    = (bf16_t*)alloc((size_t)BN_ * D_ * 2);
  bf16_t*  qkB   = (bf16_t*)alloc((size_t)BN_ * 2 * D_ * 2);  // q|k, ld 1024
  bf16_t*  vTB   = (bf16_t*)alloc((size_t)BN_ * D_ * 2);      // per-head V^T
  bf16_t*  ctxB  = (bf16_t*)alloc((size_t)BN_ * D_ * 2);

  WPrep wp;
  wp.src[0] = W_w; wp.dst[0] = WtW;
  wp.src[1] = Wq;  wp.dst[1] = WtQKV;
  wp.src[2] = Wk;  wp.dst[2] = WtQKV + (size_t)D_ * D_;
  wp.src[3] = Wv;  wp.dst[3] = WtQKV + (size_t)2 * D_ * D_;
  wp.src[4] = Wo;  wp.dst[4] = WtO;
  k_prep<<<1280, 256, 0, stream>>>(wp);   // W^T only (x-cast fused into h-GEMM)

  // h-GEMM + LayerNorm fused; A read directly from fp32 x with inline cast
  k_gemm_row<0><<<BN_ / 32, 512, 0, stream>>>(nullptr, x, WtW, W_b,
                                              ln_g, ln_b, nullptr, hB);
  // q scale folds SCALE * log2(e) so attention can use raw v_exp_f32 (exp2)
  dim3 gqkv(BN_ / 128, 3 * D_ / 128);    // 64 x 12 (128x128 tiles, R10 config)
  k_gemm_qkv<<<gqkv, 256, 0, stream>>>(hB, WtQKV, bq, bk, bv,
                                       0.125f * LOG2E, qkB, vTB);
  k_attn<<<1024, 256, 0, stream>>>(qkB, vTB, adj, use_adj, ctxB);
  // O-GEMM + ReLU + gate fused -> final fp32 output
  k_gemm_row<1><<<BN_ / 32, 512, 0, stream>>>(ctxB, nullptr, WtO, bo,
                                              x, gw, gb, d_out);
}